// Round 3
// baseline (475.984 us; speedup 1.0000x reference)
//
#include <hip/hip_runtime.h>
#include <hip/hip_bf16.h>

#define B_    4
#define S_    2048
#define HID_  1024
#define NH_   16
#define HD_   64
#define LOGITS_CAP 30.0f

typedef __attribute__((ext_vector_type(8))) short short8;
typedef __attribute__((ext_vector_type(4))) float float4v;

static __device__ __forceinline__ unsigned short f2bf(float f) {
    unsigned u = __builtin_bit_cast(unsigned, f);
    u = (u + 0x7fffu + ((u >> 16) & 1u)) >> 16;
    return (unsigned short)u;
}

// ---------------- fp32 -> bf16 conversion (vectorized) ----------------
__global__ void convert_f32_bf16(const float* __restrict__ src,
                                 unsigned short* __restrict__ dst, int n4) {
    int i = blockIdx.x * blockDim.x + threadIdx.x;
    int st = gridDim.x * blockDim.x;
    for (; i < n4; i += st) {
        float4 v = ((const float4*)src)[i];
        ushort4 o;
        o.x = f2bf(v.x); o.y = f2bf(v.y); o.z = f2bf(v.z); o.w = f2bf(v.w);
        ((ushort4*)dst)[i] = o;
    }
}

// ---------------- QKV projection GEMM ----------------
// out[m][o] = sum_h hidden[m][h] * W[o][h] + b[o]   (NT gemm, both k-contig)
// z=0 -> Q (scaled 1/8, layout [B,H,S,D])
// z=1 -> K (layout [B,H,S,D])
// z=2 -> V (layout [B,H,D,S]  transposed for attention PV)
__global__ __launch_bounds__(256) void qkv_gemm(
    const unsigned short* __restrict__ hb,
    const unsigned short* __restrict__ wqb,
    const unsigned short* __restrict__ wkb,
    const unsigned short* __restrict__ wvb,
    const float* __restrict__ bq,
    const float* __restrict__ bk,
    const float* __restrict__ bv,
    unsigned short* __restrict__ q_ws,
    unsigned short* __restrict__ k_ws,
    unsigned short* __restrict__ vt_ws) {
    const int z = blockIdx.z;
    const unsigned short* w = (z == 0) ? wqb : ((z == 1) ? wkb : wvb);
    const float* bias = (z == 0) ? bq : ((z == 1) ? bk : bv);
    const int n0 = blockIdx.x * 64;
    const int m0 = blockIdx.y * 64;

    __shared__ unsigned short Ab[64][40];  // +8 pad -> 2-way bank conflict only
    __shared__ unsigned short Bb[64][40];

    const int tid = threadIdx.x;
    const int lane = tid & 63;
    const int wid = tid >> 6;
    const int wm = wid >> 1, wn = wid & 1;

    float4v acc[2][2] = {};

    const int lrow = tid >> 2;         // 0..63
    const int lcol = (tid & 3) * 8;    // 0,8,16,24

    for (int k0 = 0; k0 < HID_; k0 += 32) {
        __syncthreads();
        *(short8*)&Ab[lrow][lcol] = *(const short8*)&hb[(size_t)(m0 + lrow) * HID_ + k0 + lcol];
        *(short8*)&Bb[lrow][lcol] = *(const short8*)&w[(size_t)(n0 + lrow) * HID_ + k0 + lcol];
        __syncthreads();

        const int kk = (lane >> 4) * 8;
        short8 af[2], bf[2];
#pragma unroll
        for (int mf = 0; mf < 2; mf++)
            af[mf] = *(const short8*)&Ab[wm * 32 + mf * 16 + (lane & 15)][kk];
#pragma unroll
        for (int nf = 0; nf < 2; nf++)
            bf[nf] = *(const short8*)&Bb[wn * 32 + nf * 16 + (lane & 15)][kk];
#pragma unroll
        for (int mf = 0; mf < 2; mf++)
#pragma unroll
            for (int nf = 0; nf < 2; nf++)
                acc[mf][nf] = __builtin_amdgcn_mfma_f32_16x16x32_bf16(af[mf], bf[nf], acc[mf][nf], 0, 0, 0);
    }

#pragma unroll
    for (int mf = 0; mf < 2; mf++)
#pragma unroll
        for (int nf = 0; nf < 2; nf++) {
            const int o = n0 + wn * 32 + nf * 16 + (lane & 15);
            const float bb = bias[o];
            const int h = o >> 6, d = o & 63;
#pragma unroll
            for (int r = 0; r < 4; r++) {
                const int m = m0 + wm * 32 + mf * 16 + (lane >> 4) * 4 + r;
                const int b = m >> 11, s = m & 2047;
                float val = acc[mf][nf][r] + bb;
                if (z == 0) val *= 0.125f;  // fold 1/sqrt(HEAD_DIM) into Q
                const unsigned short bfv = f2bf(val);
                if (z == 2)
                    vt_ws[(((size_t)(b * NH_ + h)) * HD_ + d) * S_ + s] = bfv;
                else if (z == 0)
                    q_ws[(((size_t)(b * NH_ + h)) * S_ + s) * HD_ + d] = bfv;
                else
                    k_ws[(((size_t)(b * NH_ + h)) * S_ + s) * HD_ + d] = bfv;
            }
        }
}

// ---------------- fused attention ----------------
// per block: one (b,h), 64 q rows. 4 waves x 16 q-rows.
// loop over 32 key-tiles of 64: S = Q K^T (already scaled), +mask, tanh-cap,
// relu, accumulate rowsum + ctx += P V. normalize at end.
__global__ __launch_bounds__(256) void attn_kernel(
    const unsigned short* __restrict__ q_ws,
    const unsigned short* __restrict__ k_ws,
    const unsigned short* __restrict__ vt_ws,
    const float* __restrict__ mask,
    float* __restrict__ out) {
    const int qt = blockIdx.x;  // 0..31
    const int bh = blockIdx.y;  // 0..63
    const int b = bh >> 4, h = bh & 15;
    const unsigned short* qp = q_ws + (size_t)bh * S_ * HD_;
    const unsigned short* kp = k_ws + (size_t)bh * S_ * HD_;
    const unsigned short* vp = vt_ws + (size_t)bh * HD_ * S_;
    const float* mp = mask + (size_t)b * S_;

    __shared__ unsigned short Kl[64][72];      // [key][d], +8 pad
    __shared__ unsigned short Vl[64][72];      // [d][key], +8 pad
    __shared__ unsigned short Pl[4][16][72];   // per-wave P tile [qrow][key]

    const int tid = threadIdx.x, lane = tid & 63, w = tid >> 6;
    const int kk = (lane >> 4) * 8;

    // Q A-fragments, loaded once
    short8 qf[2];
    {
        const int qrow = qt * 64 + w * 16 + (lane & 15);
        qf[0] = *(const short8*)&qp[(size_t)qrow * HD_ + kk];
        qf[1] = *(const short8*)&qp[(size_t)qrow * HD_ + 32 + kk];
    }

    float4v ctx[4] = {};
    float rs_acc[4] = {0.f, 0.f, 0.f, 0.f};

    // tile loaders: 64 rows x 64 cols = 512 short8; 256 threads -> 2 each
    const int ldrow = tid >> 3;           // 0..31  (and +32)
    const int ldcol = (tid & 7) * 8;      // 0..56

    for (int kt = 0; kt < 32; kt++) {
        __syncthreads();
        *(short8*)&Kl[ldrow][ldcol] =
            *(const short8*)&kp[(size_t)(kt * 64 + ldrow) * HD_ + ldcol];
        *(short8*)&Kl[ldrow + 32][ldcol] =
            *(const short8*)&kp[(size_t)(kt * 64 + ldrow + 32) * HD_ + ldcol];
        *(short8*)&Vl[ldrow][ldcol] =
            *(const short8*)&vp[(size_t)ldrow * S_ + kt * 64 + ldcol];
        *(short8*)&Vl[ldrow + 32][ldcol] =
            *(const short8*)&vp[(size_t)(ldrow + 32) * S_ + kt * 64 + ldcol];
        __syncthreads();

        // --- QK^T : S[16 q][64 key] per wave ---
        float4v sfr[4];
#pragma unroll
        for (int n = 0; n < 4; n++) {
            short8 kf0 = *(const short8*)&Kl[n * 16 + (lane & 15)][kk];
            short8 kf1 = *(const short8*)&Kl[n * 16 + (lane & 15)][32 + kk];
            float4v a = {};
            a = __builtin_amdgcn_mfma_f32_16x16x32_bf16(qf[0], kf0, a, 0, 0, 0);
            a = __builtin_amdgcn_mfma_f32_16x16x32_bf16(qf[1], kf1, a, 0, 0, 0);
            sfr[n] = a;
        }

        // --- mask + tanh softcap + relu; rowsum; stage P to LDS ---
        float rs4[4] = {0.f, 0.f, 0.f, 0.f};
#pragma unroll
        for (int n = 0; n < 4; n++) {
            const float mval = mp[kt * 64 + n * 16 + (lane & 15)];
#pragma unroll
            for (int r = 0; r < 4; r++) {
                float sc = sfr[n][r] + mval;
                float t = sc * (1.0f / LOGITS_CAP);
                float e = __expf(2.0f * t);
                float th = 1.0f - 2.0f / (e + 1.0f);
                float rl = fmaxf(LOGITS_CAP * th, 0.0f);
                rs4[r] += rl;
                Pl[w][(lane >> 4) * 4 + r][n * 16 + (lane & 15)] = f2bf(rl);
            }
        }
#pragma unroll
        for (int r = 0; r < 4; r++) {
            float v = rs4[r];
            v += __shfl_xor(v, 1);
            v += __shfl_xor(v, 2);
            v += __shfl_xor(v, 4);
            v += __shfl_xor(v, 8);
            rs_acc[r] += v;
        }

        // --- PV : ctx[16 q][64 d] += P[16 q][64 k] * V[64 k][64 d] ---
        short8 pf0 = *(const short8*)&Pl[w][lane & 15][kk];
        short8 pf1 = *(const short8*)&Pl[w][lane & 15][32 + kk];
#pragma unroll
        for (int n = 0; n < 4; n++) {
            short8 vf0 = *(const short8*)&Vl[n * 16 + (lane & 15)][kk];
            short8 vf1 = *(const short8*)&Vl[n * 16 + (lane & 15)][32 + kk];
            ctx[n] = __builtin_amdgcn_mfma_f32_16x16x32_bf16(pf0, vf0, ctx[n], 0, 0, 0);
            ctx[n] = __builtin_amdgcn_mfma_f32_16x16x32_bf16(pf1, vf1, ctx[n], 0, 0, 0);
        }
    }

    // --- normalize and write out [B,S,HID] fp32 ---
#pragma unroll
    for (int n = 0; n < 4; n++) {
        const int d = n * 16 + (lane & 15);
#pragma unroll
        for (int r = 0; r < 4; r++) {
            const int qrow = qt * 64 + w * 16 + (lane >> 4) * 4 + r;
            const float val = ctx[n][r] / (rs_acc[r] + 1e-6f);
            out[((size_t)b * S_ + qrow) * HID_ + h * HD_ + d] = val;
        }
    }
}

extern "C" void kernel_launch(void* const* d_in, const int* in_sizes, int n_in,
                              void* d_out, int out_size, void* d_ws, size_t ws_size,
                              hipStream_t stream) {
    const float* hidden = (const float*)d_in[0];
    const float* mask   = (const float*)d_in[1];
    const float* Wq     = (const float*)d_in[2];
    const float* bq     = (const float*)d_in[3];
    const float* Wk     = (const float*)d_in[4];
    const float* bk     = (const float*)d_in[5];
    const float* Wv     = (const float*)d_in[6];
    const float* bv     = (const float*)d_in[7];
    float* out = (float*)d_out;

    char* ws = (char*)d_ws;
    const size_t HB_BYTES = (size_t)B_ * S_ * HID_ * 2;      // 16 MiB
    const size_t W_BYTES  = (size_t)HID_ * HID_ * 2;         // 2 MiB
    const size_t QKV_BYTES = (size_t)B_ * NH_ * S_ * HD_ * 2;  // 16 MiB

    unsigned short* hb    = (unsigned short*)(ws);
    unsigned short* wqb   = (unsigned short*)(ws + HB_BYTES);
    unsigned short* wkb   = (unsigned short*)(ws + HB_BYTES + W_BYTES);
    unsigned short* wvb   = (unsigned short*)(ws + HB_BYTES + 2 * W_BYTES);
    unsigned short* q_wsp = (unsigned short*)(ws + HB_BYTES + 3 * W_BYTES);
    unsigned short* k_wsp = (unsigned short*)(ws + HB_BYTES + 3 * W_BYTES + QKV_BYTES);
    unsigned short* vt_wsp = (unsigned short*)(ws + HB_BYTES + 3 * W_BYTES + 2 * QKV_BYTES);

    // fp32 -> bf16 conversions
    convert_f32_bf16<<<2048, 256, 0, stream>>>(hidden, hb, (B_ * S_ * HID_) / 4);
    convert_f32_bf16<<<1024, 256, 0, stream>>>(Wq, wqb, (HID_ * HID_) / 4);
    convert_f32_bf16<<<1024, 256, 0, stream>>>(Wk, wkb, (HID_ * HID_) / 4);
    convert_f32_bf16<<<1024, 256, 0, stream>>>(Wv, wvb, (HID_ * HID_) / 4);

    // QKV projections
    dim3 ggrid(HID_ / 64, (B_ * S_) / 64, 3);
    qkv_gemm<<<ggrid, 256, 0, stream>>>(hb, wqb, wkb, wvb, bq, bk, bv,
                                        q_wsp, k_wsp, vt_wsp);

    // fused attention
    dim3 agrid(S_ / 64, B_ * NH_);
    attn_kernel<<<agrid, 256, 0, stream>>>(q_wsp, k_wsp, vt_wsp, mask, out);
}

// Round 4
// 329.985 us; speedup vs baseline: 1.4424x; 1.4424x over previous
//
#include <hip/hip_runtime.h>
#include <hip/hip_bf16.h>

#define B_    4
#define S_    2048
#define HID_  1024
#define NH_   16
#define HD_   64
#define LOGITS_CAP 30.0f
// 30*tanh(x/30) = 30 - 60/(exp2(x*K1)+1),  K1 = 2*log2(e)/30
#define K1_   0.09617966939259756f

typedef __attribute__((ext_vector_type(8))) short short8;
typedef __attribute__((ext_vector_type(4))) float float4v;

static __device__ __forceinline__ unsigned short f2bf(float f) {
    unsigned u = __builtin_bit_cast(unsigned, f);
    u = (u + 0x7fffu + ((u >> 16) & 1u)) >> 16;
    return (unsigned short)u;
}

// ---------------- fp32 -> bf16 conversion (all 4 tensors, one launch) ----------
__global__ void convert_all(const float* __restrict__ h,
                            const float* __restrict__ wq,
                            const float* __restrict__ wk,
                            const float* __restrict__ wv,
                            unsigned short* __restrict__ hb,
                            unsigned short* __restrict__ wqb,
                            unsigned short* __restrict__ wkb,
                            unsigned short* __restrict__ wvb) {
    const int which = blockIdx.y;
    const float* src = (which == 0) ? h : (which == 1) ? wq : (which == 2) ? wk : wv;
    unsigned short* dst = (which == 0) ? hb : (which == 1) ? wqb : (which == 2) ? wkb : wvb;
    const int n4 = ((which == 0) ? (B_ * S_ * HID_) : (HID_ * HID_)) / 4;
    int i = blockIdx.x * blockDim.x + threadIdx.x;
    const int st = gridDim.x * blockDim.x;
    for (; i < n4; i += st) {
        float4 v = ((const float4*)src)[i];
        ushort4 o;
        o.x = f2bf(v.x); o.y = f2bf(v.y); o.z = f2bf(v.z); o.w = f2bf(v.w);
        ((ushort4*)dst)[i] = o;
    }
}

// ---------------- QKV projection GEMM (m97 structure) ----------------
// 128x128 tile, BK=32, 4 waves (2x2), wave tile 64x64 = 4x4 16x16x32 frags.
// global_load_lds width=16 into LINEAR LDS tiles (no pad).
// z=0 -> Q (scaled 1/8, [B,H,S,D]); z=1 -> K ([B,H,S,D]); z=2 -> V^T ([B,H,D,S])
__global__ __launch_bounds__(256) void qkv_gemm(
    const unsigned short* __restrict__ hb,
    const unsigned short* __restrict__ wqb,
    const unsigned short* __restrict__ wkb,
    const unsigned short* __restrict__ wvb,
    const float* __restrict__ bq,
    const float* __restrict__ bk,
    const float* __restrict__ bv,
    unsigned short* __restrict__ q_ws,
    unsigned short* __restrict__ k_ws,
    unsigned short* __restrict__ vt_ws) {
    const int z = blockIdx.z;
    const unsigned short* wgt = (z == 0) ? wqb : ((z == 1) ? wkb : wvb);
    const float* bias = (z == 0) ? bq : ((z == 1) ? bk : bv);
    const int n0 = blockIdx.x * 128;
    const int m0 = blockIdx.y * 128;

    __shared__ unsigned short As[128 * 32];  // linear, row-major [128][32]
    __shared__ unsigned short Bs[128 * 32];

    const int tid = threadIdx.x;
    const int lane = tid & 63;
    const int w = tid >> 6;
    const int wm = w >> 1, wn = w & 1;

    float4v acc[4][4] = {};

    // per-lane global source offsets for staging (lane covers 16B)
    const int srow = (lane >> 2);        // 0..15 within a 16-row chunk
    const int scol = (lane & 3) * 8;     // 0,8,16,24

    for (int k0 = 0; k0 < HID_; k0 += 32) {
        // stage A rows [w*32 .. w*32+31], B rows likewise (2 issues each)
#pragma unroll
        for (int j = 0; j < 2; j++) {
            const int row = w * 32 + j * 16 + srow;
            const unsigned short* gA = &hb[(size_t)(m0 + row) * HID_ + k0 + scol];
            const unsigned short* gB = &wgt[(size_t)(n0 + row) * HID_ + k0 + scol];
            __builtin_amdgcn_global_load_lds(
                (const __attribute__((address_space(1))) unsigned int*)gA,
                (__attribute__((address_space(3))) unsigned int*)((char*)As + (w * 32 + j * 16) * 64),
                16, 0, 0);
            __builtin_amdgcn_global_load_lds(
                (const __attribute__((address_space(1))) unsigned int*)gB,
                (__attribute__((address_space(3))) unsigned int*)((char*)Bs + (w * 32 + j * 16) * 64),
                16, 0, 0);
        }
        __syncthreads();  // compiler drains vmcnt(0) before barrier

        const int kk = (lane >> 4) * 8;
        short8 af[4], bf[4];
#pragma unroll
        for (int mf = 0; mf < 4; mf++)
            af[mf] = *(const short8*)((const char*)As + (wm * 64 + mf * 16 + (lane & 15)) * 64 + kk * 2);
#pragma unroll
        for (int nf = 0; nf < 4; nf++)
            bf[nf] = *(const short8*)((const char*)Bs + (wn * 64 + nf * 16 + (lane & 15)) * 64 + kk * 2);
#pragma unroll
        for (int mf = 0; mf < 4; mf++)
#pragma unroll
            for (int nf = 0; nf < 4; nf++)
                acc[mf][nf] = __builtin_amdgcn_mfma_f32_16x16x32_bf16(af[mf], bf[nf], acc[mf][nf], 0, 0, 0);
        __syncthreads();
    }

#pragma unroll
    for (int mf = 0; mf < 4; mf++)
#pragma unroll
        for (int nf = 0; nf < 4; nf++) {
            const int o = n0 + wn * 64 + nf * 16 + (lane & 15);
            const float bb = bias[o];
            const int h = o >> 6, d = o & 63;
#pragma unroll
            for (int r = 0; r < 4; r++) {
                const int m = m0 + wm * 64 + mf * 16 + (lane >> 4) * 4 + r;
                const int b = m >> 11, s = m & 2047;
                float val = acc[mf][nf][r] + bb;
                if (z == 0) val *= 0.125f;  // fold 1/sqrt(HEAD_DIM) into Q
                const unsigned short bfv = f2bf(val);
                if (z == 2)
                    vt_ws[(((size_t)(b * NH_ + h)) * HD_ + d) * S_ + s] = bfv;
                else if (z == 0)
                    q_ws[(((size_t)(b * NH_ + h)) * S_ + s) * HD_ + d] = bfv;
                else
                    k_ws[(((size_t)(b * NH_ + h)) * S_ + s) * HD_ + d] = bfv;
            }
        }
}

// ---------------- fused attention ----------------
// per block: one (b,h), 64 q rows. 4 waves x 16 q-rows. 32 key-tiles of 64.
__global__ __launch_bounds__(256) void attn_kernel(
    const unsigned short* __restrict__ q_ws,
    const unsigned short* __restrict__ k_ws,
    const unsigned short* __restrict__ vt_ws,
    const float* __restrict__ mask,
    float* __restrict__ out) {
    const int qt = blockIdx.x;  // 0..31
    const int bh = blockIdx.y;  // 0..63
    const int b = bh >> 4, h = bh & 15;
    const unsigned short* qp = q_ws + (size_t)bh * S_ * HD_;
    const unsigned short* kp = k_ws + (size_t)bh * S_ * HD_;
    const unsigned short* vp = vt_ws + (size_t)bh * HD_ * S_;
    const float* mp = mask + (size_t)b * S_;

    __shared__ unsigned short Kl[64][72];      // [key][d], +8 pad
    __shared__ unsigned short Vl[64][72];      // [d][key], +8 pad
    __shared__ unsigned short Pl[4][16][72];   // per-wave P tile [qrow][key]

    const int tid = threadIdx.x, lane = tid & 63, w = tid >> 6;
    const int kk = (lane >> 4) * 8;
    const int l15 = lane & 15;

    // Q A-fragments, loaded once
    short8 qf[2];
    {
        const int qrow = qt * 64 + w * 16 + l15;
        qf[0] = *(const short8*)&qp[(size_t)qrow * HD_ + kk];
        qf[1] = *(const short8*)&qp[(size_t)qrow * HD_ + 32 + kk];
    }

    float4v ctx[4] = {};
    float rs_acc[4] = {0.f, 0.f, 0.f, 0.f};   // per-lane partials; reduced after loop

    // tile loaders: 64 rows x 64 cols = 512 short8; 256 threads -> 2 each
    const int ldrow = tid >> 3;           // 0..31  (and +32)
    const int ldcol = (tid & 7) * 8;      // 0..56

    for (int kt = 0; kt < 32; kt++) {
        __syncthreads();
        *(short8*)&Kl[ldrow][ldcol] =
            *(const short8*)&kp[(size_t)(kt * 64 + ldrow) * HD_ + ldcol];
        *(short8*)&Kl[ldrow + 32][ldcol] =
            *(const short8*)&kp[(size_t)(kt * 64 + ldrow + 32) * HD_ + ldcol];
        *(short8*)&Vl[ldrow][ldcol] =
            *(const short8*)&vp[(size_t)ldrow * S_ + kt * 64 + ldcol];
        *(short8*)&Vl[ldrow + 32][ldcol] =
            *(const short8*)&vp[(size_t)(ldrow + 32) * S_ + kt * 64 + ldcol];
        __syncthreads();

        // --- QK^T : S[16 q][64 key] per wave ---
        float4v sfr[4];
#pragma unroll
        for (int n = 0; n < 4; n++) {
            short8 kf0 = *(const short8*)&Kl[n * 16 + l15][kk];
            short8 kf1 = *(const short8*)&Kl[n * 16 + l15][32 + kk];
            float4v a = {};
            a = __builtin_amdgcn_mfma_f32_16x16x32_bf16(qf[0], kf0, a, 0, 0, 0);
            a = __builtin_amdgcn_mfma_f32_16x16x32_bf16(qf[1], kf1, a, 0, 0, 0);
            sfr[n] = a;
        }

        // --- softcap+relu (folded): p = max(30 - 60*rcp(exp2(t)+1), 0),
        //     t = s*K1 + m*K1 ; accumulate per-lane rowsum; pack & stage P ---
        const float* mrow = mp + kt * 64 + l15;
#pragma unroll
        for (int n = 0; n < 4; n++) {
            const float mk = mrow[n * 16] * K1_;
            float rl[4];
#pragma unroll
            for (int r = 0; r < 4; r++) {
                float t = __builtin_fmaf(sfr[n][r], K1_, mk);
                float e = __builtin_amdgcn_exp2f(t);
                float rc = __builtin_amdgcn_rcpf(e + 1.0f);
                rl[r] = fmaxf(__builtin_fmaf(-60.0f, rc, 30.0f), 0.0f);
                rs_acc[r] += rl[r];
            }
            unsigned int d01, d23;
            asm("v_cvt_pk_bf16_f32 %0, %1, %2" : "=v"(d01) : "v"(rl[0]), "v"(rl[1]));
            asm("v_cvt_pk_bf16_f32 %0, %1, %2" : "=v"(d23) : "v"(rl[2]), "v"(rl[3]));
            unsigned short* pr = &Pl[w][(lane >> 4) * 4][n * 16 + l15];
            pr[0]       = (unsigned short)d01;
            pr[72]      = (unsigned short)(d01 >> 16);
            pr[144]     = (unsigned short)d23;
            pr[216]     = (unsigned short)(d23 >> 16);
        }

        // --- PV : ctx[16 q][64 d] += P[16 q][64 k] * V[64 k][64 d] ---
        short8 pf0 = *(const short8*)&Pl[w][l15][kk];
        short8 pf1 = *(const short8*)&Pl[w][l15][32 + kk];
#pragma unroll
        for (int n = 0; n < 4; n++) {
            short8 vf0 = *(const short8*)&Vl[n * 16 + l15][kk];
            short8 vf1 = *(const short8*)&Vl[n * 16 + l15][32 + kk];
            ctx[n] = __builtin_amdgcn_mfma_f32_16x16x32_bf16(pf0, vf0, ctx[n], 0, 0, 0);
            ctx[n] = __builtin_amdgcn_mfma_f32_16x16x32_bf16(pf1, vf1, ctx[n], 0, 0, 0);
        }
    }

    // --- deferred rowsum reduce (once) + normalize + write [B,S,HID] fp32 ---
    float rinv[4];
#pragma unroll
    for (int r = 0; r < 4; r++) {
        float v = rs_acc[r];
        v += __shfl_xor(v, 1);
        v += __shfl_xor(v, 2);
        v += __shfl_xor(v, 4);
        v += __shfl_xor(v, 8);
        rinv[r] = __builtin_amdgcn_rcpf(v + 1e-6f);
    }
#pragma unroll
    for (int n = 0; n < 4; n++) {
        const int d = n * 16 + l15;
#pragma unroll
        for (int r = 0; r < 4; r++) {
            const int qrow = qt * 64 + w * 16 + (lane >> 4) * 4 + r;
            out[((size_t)b * S_ + qrow) * HID_ + h * HD_ + d] = ctx[n][r] * rinv[r];
        }
    }
}

extern "C" void kernel_launch(void* const* d_in, const int* in_sizes, int n_in,
                              void* d_out, int out_size, void* d_ws, size_t ws_size,
                              hipStream_t stream) {
    const float* hidden = (const float*)d_in[0];
    const float* mask   = (const float*)d_in[1];
    const float* Wq     = (const float*)d_in[2];
    const float* bq     = (const float*)d_in[3];
    const float* Wk     = (const float*)d_in[4];
    const float* bk     = (const float*)d_in[5];
    const float* Wv     = (const float*)d_in[6];
    const float* bv     = (const float*)d_in[7];
    float* out = (float*)d_out;

    char* ws = (char*)d_ws;
    const size_t HB_BYTES = (size_t)B_ * S_ * HID_ * 2;      // 16 MiB
    const size_t W_BYTES  = (size_t)HID_ * HID_ * 2;         // 2 MiB
    const size_t QKV_BYTES = (size_t)B_ * NH_ * S_ * HD_ * 2;  // 16 MiB

    unsigned short* hb    = (unsigned short*)(ws);
    unsigned short* wqb   = (unsigned short*)(ws + HB_BYTES);
    unsigned short* wkb   = (unsigned short*)(ws + HB_BYTES + W_BYTES);
    unsigned short* wvb   = (unsigned short*)(ws + HB_BYTES + 2 * W_BYTES);
    unsigned short* q_wsp = (unsigned short*)(ws + HB_BYTES + 3 * W_BYTES);
    unsigned short* k_wsp = (unsigned short*)(ws + HB_BYTES + 3 * W_BYTES + QKV_BYTES);
    unsigned short* vt_wsp = (unsigned short*)(ws + HB_BYTES + 3 * W_BYTES + 2 * QKV_BYTES);

    // fp32 -> bf16 conversions, one launch
    dim3 cgrid(1024, 4);
    convert_all<<<cgrid, 256, 0, stream>>>(hidden, Wq, Wk, Wv, hb, wqb, wkb, wvb);

    // QKV projections (128x128 tiles)
    dim3 ggrid(HID_ / 128, (B_ * S_) / 128, 3);
    qkv_gemm<<<ggrid, 256, 0, stream>>>(hb, wqb, wkb, wvb, bq, bk, bv,
                                        q_wsp, k_wsp, vt_wsp);

    // fused attention
    dim3 agrid(S_ / 64, B_ * NH_);
    attn_kernel<<<agrid, 256, 0, stream>>>(q_wsp, k_wsp, vt_wsp, mask, out);
}